// Round 9
// baseline (152.591 us; speedup 1.0000x reference)
//
#include <hip/hip_runtime.h>

#define BINS 10
#define TPB 256
#define NW (TPB / 64)       // 4 waves per block
#define MAX_BLOCKS 1024     // 4 blocks/CU (LDS 32KB/block; 128KB/CU of 160KB)
#define NTHR 9              // bin thresholds k=1..9 in u-space
#define Q 2                 // vec4 groups per lane per tile
#define CALLS (2 * Q)       // global_load_lds instructions per wave per tile (x+t)

typedef float f32x4 __attribute__((ext_vector_type(4)));
typedef int   i32x4 __attribute__((ext_vector_type(4)));

static_assert(CALLS == 4, "WAITV literals below assume 4 staging calls/tile");

// u-space bin boundaries: c_k = ln(k / (9.9999 - k))  (logit of k/9.9999).
// bin(sigmoid(u)) >= k  <=>  u >= c_k   (sigmoid monotone).
__device__ __constant__ const float c_thr[NTHR] = {
    -2.1972135f, -1.3862819f, -0.8472836f, -0.4054484f, 2.00002e-5f,
     0.4054901f,  0.8473312f,  1.3863444f,  2.1973246f
};

// Register-resident suffix-histogram accumulate.
// A[0]  += ce (total);  A[k] += ce*(u>=c_k);  C[k-1] += (u>=c_k), k=1..9.
__device__ __forceinline__ void ghmc_accum(float z, int t, float* A, float* C) {
    // t in {0,1}:  g = |sigmoid(z)-t| = sigmoid(u),  ce = softplus(u),
    // with u = (t ? -z : z) = z with sign bit xor'd by t.
    unsigned ub = __float_as_uint(z) ^ ((unsigned)t << 31);
    float u  = __uint_as_float(ub);
    float e  = __expf(-fabsf(u));                  // v_mul + v_exp
    float q  = 1.0f + e;
    float ce = fmaxf(u, 0.0f) + __logf(q);         // v_max + v_log(+mul) + v_add
    A[0] += ce;
    #pragma unroll
    for (int k = 1; k <= NTHR; ++k) {
        float m = (u >= c_thr[k - 1]) ? 1.0f : 0.0f;  // v_cmp + v_cndmask
        A[k]    = fmaf(m, ce, A[k]);                  // v_fma
        C[k - 1] += m;                                // v_add
    }
}

// Hand-counted wait (never 0 inside the loop) + rule-#18 scheduling fence.
#define WAITV(n) do {                                             \
    asm volatile("s_waitcnt vmcnt(" #n ")" ::: "memory");         \
    __builtin_amdgcn_sched_barrier(0);                            \
} while (0)

__global__ __launch_bounds__(TPB, 4) void ghmc_main(const float* __restrict__ x,
                                                    const int* __restrict__ tgt,
                                                    float* __restrict__ partial,  // [gridDim.x][2*BINS]
                                                    int nvec, int ntotal) {
    float A[BINS];   // A[0]=total ce, A[k]=suffix ce-sum for threshold k
    float C[NTHR];   // suffix counts for thresholds 1..9
    #pragma unroll
    for (int b = 0; b < BINS; ++b) A[b] = 0.0f;
    #pragma unroll
    for (int k = 0; k < NTHR; ++k) C[k] = 0.0f;

    const f32x4* __restrict__ x4 = (const f32x4*)x;
    const i32x4* __restrict__ t4 = (const i32x4*)tgt;
    const int tid  = threadIdx.x;
    const int wid  = tid >> 6;
    const int lane = tid & 63;

    // Per-wave-private double-buffered staging tiles. Each wave stages its
    // own slice with global_load_lds and computes ONLY from that slice:
    // no __syncthreads anywhere in the stream loop -> the compiler has no
    // barrier to hang a pipeline-collapsing vmcnt(0) on, and there are no
    // cross-wave races by construction. 2*(2+2) KB/wave * 4 waves = 32 KB.
    __shared__ f32x4 ldsx[2][NW][Q][64];
    __shared__ i32x4 ldst[2][NW][Q][64];

    // Tile t of this block covers vec4 groups [(t*grid + bid)*GPB, +GPB).
    const int GPB    = TPB * Q;                       // 512 groups per block-tile
    const int ntiles = nvec / (GPB * gridDim.x);      // = 8 for N=2^24, 1024 blocks
    const int covered = ntiles * GPB * gridDim.x;

    // Stage one tile: CALLS=4 global_load_lds (x0,t0,x1,t1). LDS dest is
    // wave-uniform base + lane*16; global src is per-lane. Lane l's group j
    // lands at lds*[b][wid][j][l] — exactly where l reads it back.
    #define STAGE(b, tb) do {                                                  \
        int _g = (tb) + wid * (Q * 64) + lane;                                 \
        _Pragma("unroll")                                                      \
        for (int _j = 0; _j < Q; ++_j) {                                       \
            __builtin_amdgcn_global_load_lds(                                  \
                (const __attribute__((address_space(1))) void*)(x4 + _g + _j * 64), \
                (__attribute__((address_space(3))) void*)&ldsx[b][wid][_j][0], \
                16, 0, 0);                                                     \
            __builtin_amdgcn_global_load_lds(                                  \
                (const __attribute__((address_space(1))) void*)(t4 + _g + _j * 64), \
                (__attribute__((address_space(3))) void*)&ldst[b][wid][_j][0], \
                16, 0, 0);                                                     \
        }                                                                      \
    } while (0)

    #define CTILE(b) do {                                                      \
        _Pragma("unroll")                                                      \
        for (int _j = 0; _j < Q; ++_j) {                                       \
            f32x4 xv = ldsx[b][wid][_j][lane];                                 \
            i32x4 tv = ldst[b][wid][_j][lane];                                 \
            ghmc_accum(xv.x, tv.x, A, C);                                      \
            ghmc_accum(xv.y, tv.y, A, C);                                      \
            ghmc_accum(xv.z, tv.z, A, C);                                      \
            ghmc_accum(xv.w, tv.w, A, C);                                      \
        }                                                                      \
    } while (0)

    if (ntiles > 0) {
        STAGE(0, (0 * gridDim.x + blockIdx.x) * GPB);          // prologue: tile 0
        for (int t = 0; t < ntiles; ++t) {
            int cur = t & 1;
            if (t + 1 < ntiles) {
                STAGE(cur ^ 1, ((t + 1) * gridDim.x + blockIdx.x) * GPB);
                // Wait for tile t's 4 calls only; tile t+1's 4 stay in
                // flight through the whole compute phase below (T4).
                WAITV(4);
            } else {
                WAITV(0);                                      // final drain
            }
            CTILE(cur);
        }
    }
    // Residual vec4 groups [covered, nvec) — grid-stride; no-op for N = 2^24.
    for (int g = covered + blockIdx.x * TPB + tid; g < nvec; g += gridDim.x * TPB) {
        f32x4 xv = x4[g];
        i32x4 tv = t4[g];
        ghmc_accum(xv.x, tv.x, A, C);
        ghmc_accum(xv.y, tv.y, A, C);
        ghmc_accum(xv.z, tv.z, A, C);
        ghmc_accum(xv.w, tv.w, A, C);
    }
    // Scalar tail (N not a multiple of 4) — no-op for N = 2^24.
    if (blockIdx.x == 0) {
        for (int i = nvec * 4 + tid; i < ntotal; i += TPB)
            ghmc_accum(x[i], tgt[i], A, C);
    }

    // Wave-level shuffle reduce (64 lanes), then tiny LDS combine of the 4 waves.
    #pragma unroll
    for (int b = 0; b < BINS; ++b) {
        #pragma unroll
        for (int o = 32; o > 0; o >>= 1) A[b] += __shfl_down(A[b], o);
    }
    #pragma unroll
    for (int k = 0; k < NTHR; ++k) {
        #pragma unroll
        for (int o = 32; o > 0; o >>= 1) C[k] += __shfl_down(C[k], o);
    }
    __shared__ float red[NW][2 * BINS];   // 320 B
    if (lane == 0) {
        #pragma unroll
        for (int b = 0; b < BINS; ++b) red[wid][b] = A[b];
        #pragma unroll
        for (int k = 0; k < NTHR; ++k) red[wid][BINS + k] = C[k];
    }
    __syncthreads();
    if (tid < BINS + NTHR) {
        float v = 0.0f;
        #pragma unroll
        for (int w = 0; w < NW; ++w) v += red[w][tid];
        partial[blockIdx.x * (2 * BINS) + tid] = v;   // per-block partials: no atomics
    }
}

// Recover per-bin sums/counts from suffix accumulators, then
// result = sum_b sum_ce_b / max(cnt_b * nonempty, 1e-6)   (the N in beta cancels)
__global__ __launch_bounds__(TPB) void ghmc_final(const float* __restrict__ partial,
                                                  float* __restrict__ out,
                                                  int nblocks, int ntotal) {
    float acc[2 * BINS];
    #pragma unroll
    for (int k = 0; k < 2 * BINS; ++k) acc[k] = 0.0f;
    for (int row = threadIdx.x; row < nblocks; row += TPB) {
        const float* p = partial + row * (2 * BINS);
        #pragma unroll
        for (int k = 0; k < 2 * BINS; ++k) acc[k] += p[k];
    }
    #pragma unroll
    for (int k = 0; k < 2 * BINS; ++k) {
        #pragma unroll
        for (int o = 32; o > 0; o >>= 1) acc[k] += __shfl_down(acc[k], o);
    }
    __shared__ float red[TPB / 64][2 * BINS];
    const int wid = threadIdx.x >> 6, lane = threadIdx.x & 63;
    if (lane == 0) {
        #pragma unroll
        for (int k = 0; k < 2 * BINS; ++k) red[wid][k] = acc[k];
    }
    __syncthreads();
    if (threadIdx.x == 0) {
        float A[BINS + 1], C[BINS + 1];
        #pragma unroll
        for (int b = 0; b < BINS; ++b) {
            float v = 0.0f;
            #pragma unroll
            for (int w = 0; w < TPB / 64; ++w) v += red[w][b];
            A[b] = v;
        }
        A[BINS] = 0.0f;
        C[0] = (float)ntotal;          // exact: ntotal <= 2^24
        #pragma unroll
        for (int k = 1; k <= NTHR; ++k) {
            float v = 0.0f;
            #pragma unroll
            for (int w = 0; w < TPB / 64; ++w) v += red[w][BINS + k - 1];
            C[k] = v;
        }
        C[BINS] = 0.0f;
        float ne = 0.0f;
        #pragma unroll
        for (int b = 0; b < BINS; ++b) {
            float c = C[b] - C[b + 1];
            ne += (c > 0.0f) ? 1.0f : 0.0f;
        }
        float res = 0.0f;
        #pragma unroll
        for (int b = 0; b < BINS; ++b) {
            float s = A[b] - A[b + 1];
            float c = C[b] - C[b + 1];
            res += s / fmaxf(c * ne, 1e-6f);
        }
        out[0] = res;
    }
}

extern "C" void kernel_launch(void* const* d_in, const int* in_sizes, int n_in,
                              void* d_out, int out_size, void* d_ws, size_t ws_size,
                              hipStream_t stream) {
    const float* x   = (const float*)d_in[0];
    const int*   tgt = (const int*)d_in[1];
    float* out     = (float*)d_out;
    float* partial = (float*)d_ws;

    int N    = in_sizes[0];
    int nvec = N / 4;

    int blocks = MAX_BLOCKS;
    int maxrows = (int)(ws_size / (2 * BINS * sizeof(float)));   // stay inside workspace
    if (blocks > maxrows) blocks = maxrows;
    int need = (nvec + TPB - 1) / TPB;
    if (blocks > need) blocks = need;
    if (blocks < 1) blocks = 1;

    ghmc_main<<<blocks, TPB, 0, stream>>>(x, tgt, partial, nvec, N);
    ghmc_final<<<1, TPB, 0, stream>>>(partial, out, blocks, N);
}